// Round 13
// baseline (333.958 us; speedup 1.0000x reference)
//
#include <hip/hip_runtime.h>
#include <hip/hip_bf16.h>
#include <hip/hip_cooperative_groups.h>

namespace cg = cooperative_groups;

#define NN 50000
#define CIN 128
#define HH 4
#define DD 32
#define HD 128
#define EE 800000
#define NEG 0.2f

typedef unsigned short ushortT;
typedef unsigned int uintT;
typedef __attribute__((ext_vector_type(8))) short bf16x8;
typedef __attribute__((ext_vector_type(4))) float f32x4;

// ---------------------------------------------------------------------------
// ws layout (units of 4B):
//   [0]       : flag (1 = edge_index is int64, 0 = int32)
//   CNT_OFF  = 16       : per-node in-degree (excl self) (NN ints)
//   FILL_OFF = 50016    : scatter fill counters (NN ints)   [cnt+fill contiguous]
//   ROW_OFF  = 100032   : CSR row offsets (NN+1 ints)
//   ESRC_OFF = 150048   : dst-sorted src indices (EE ints)
//   BTOT_OFF = 1000048  : scan block totals (64 ints)
//   WBF_OFF  = 1000112  : W bf16 [256][128] (16384 float-slots)
//   XPH_OFF  = 1016496  : interleaved bf16 rows xl|xr [NN][256] (3.2M slots)
// ---------------------------------------------------------------------------
#define CNT_OFF  16
#define FILL_OFF 50016
#define ROW_OFF  100032
#define ESRC_OFF 150048
#define BTOT_OFF 1000048
#define WBF_OFF  1000112
#define XPH_OFF  1016496
#define SCAN_NB  49          // ceil((NN+1)/1024)

__device__ __forceinline__ ushortT f2bf(float f) {
    uintT u = __float_as_uint(f);
    u = (u + 0x7fff + ((u >> 16) & 1)) >> 16;   // RNE
    return (ushortT)u;
}
__device__ __forceinline__ float bflo(uintT u) { return __uint_as_float(u << 16); }
__device__ __forceinline__ float bfhi(uintT u) { return __uint_as_float(u & 0xffff0000u); }

// ---------------------------------------------------------------------------
// Cooperative fused prep: detect | zero | hist+wprep | scan | scan-combine |
// offset-add | scatter.  256 blocks x 1024 threads (co-resident, 16 waves/CU).
// ---------------------------------------------------------------------------
__global__ __launch_bounds__(1024) void prep_kernel(
    const int* __restrict__ ei_raw, const float* __restrict__ Wl,
    const float* __restrict__ Wr, int* __restrict__ flag,
    int* __restrict__ cnt, int* __restrict__ fill, int* __restrict__ row,
    int* __restrict__ esrc, int* __restrict__ btot, ushortT* __restrict__ wbf)
{
    cg::grid_group grid = cg::this_grid();
    __shared__ int wtot[16];
    const int gtid = blockIdx.x * 1024 + threadIdx.x;
    const int gsz  = gridDim.x * 1024;

    // P0: int64/int32 detect (block 0) + zero cnt/fill (contiguous 2*NN)
    if (blockIdx.x == 0 && threadIdx.x < 64) {
        const int w = ei_raw[2 * threadIdx.x + 1];
        const unsigned long long b = __ballot(w != 0);
        if (threadIdx.x == 0) flag[0] = (b == 0ULL) ? 1 : 0;
    }
    for (int i = gtid; i < 2 * NN; i += gsz) cnt[i] = 0;
    grid.sync();

    const int f = flag[0];
    // P1: dst histogram; idle-block fold-in of W f32->bf16 conversion
    for (int e = gtid; e < EE; e += gsz) {
        const int d = f ? ei_raw[2 * (EE + e)] : ei_raw[EE + e];
        atomicAdd(&cnt[d], 1);
    }
    if (blockIdx.x >= 252) {
        const int i = (blockIdx.x - 252) * 1024 + threadIdx.x;   // 0..4095
        const float* src = (i < 2048) ? Wl : Wr;
        const int off = (i < 2048) ? i : i - 2048;
        const float4 v0 = *(const float4*)(src + (size_t)off * 8);
        const float4 v1 = *(const float4*)(src + (size_t)off * 8 + 4);
        bf16x8 o;
        o[0] = f2bf(v0.x); o[1] = f2bf(v0.y); o[2] = f2bf(v0.z); o[3] = f2bf(v0.w);
        o[4] = f2bf(v1.x); o[5] = f2bf(v1.y); o[6] = f2bf(v1.z); o[7] = f2bf(v1.w);
        *(bf16x8*)(wbf + ((i < 2048) ? 0 : 16384) + (size_t)off * 8) = o;
    }
    grid.sync();

    // P2: block-local exclusive scan (blocks 0..48, 1024 elems each)
    if (blockIdx.x < SCAN_NB) {
        const int t = threadIdx.x, lane = t & 63, wv = t >> 6;
        const int i = blockIdx.x * 1024 + t;
        const int v = (i < NN) ? cnt[i] : 0;
        int acc = v;
        #pragma unroll
        for (int off = 1; off < 64; off <<= 1) {
            const int u = __shfl_up(acc, off, 64);
            if (lane >= off) acc += u;
        }
        if (lane == 63) wtot[wv] = acc;
        __syncthreads();
        if (wv == 0 && lane < 16) {
            const int wvv = wtot[lane];
            int wacc = wvv;
            #pragma unroll
            for (int off = 1; off < 16; off <<= 1) {
                const int u = __shfl_up(wacc, off, 64);
                if (lane >= off) wacc += u;
            }
            wtot[lane] = wacc - wvv;        // exclusive wave offset
        }
        __syncthreads();
        const int ex = wtot[wv] + acc - v;  // block-local exclusive prefix
        if (i <= NN) row[i] = ex;
        if (t == 1023) btot[blockIdx.x] = ex + v;
    }
    grid.sync();

    // P3: block 0 converts btot to exclusive
    if (blockIdx.x == 0 && threadIdx.x < 64) {
        const int lane = threadIdx.x;
        const int v = (lane < SCAN_NB) ? btot[lane] : 0;
        int acc = v;
        #pragma unroll
        for (int off = 1; off < 64; off <<= 1) {
            const int u = __shfl_up(acc, off, 64);
            if (lane >= off) acc += u;
        }
        if (lane < SCAN_NB) btot[lane] = acc - v;
    }
    grid.sync();

    // P4: add block offsets
    for (int i = gtid; i <= NN; i += gsz) row[i] += btot[i >> 10];
    grid.sync();

    // P5: scatter src into dst segments
    for (int e = gtid; e < EE; e += gsz) {
        int s, d;
        if (f) { s = ei_raw[2 * e]; d = ei_raw[2 * (EE + e)]; }
        else   { s = ei_raw[e];     d = ei_raw[EE + e]; }
        const int pos = row[d] + atomicAdd(&fill[d], 1);
        esrc[pos] = s;
    }
}

// ---------------------------------------------------------------------------
// MFMA GEMM with fused f32->bf16 x conversion via LDS staging.
// Block = 256 thr = 4 waves; computes 32 rows x 256 cols (all parts/halves).
// ---------------------------------------------------------------------------
__global__ __launch_bounds__(256) void gemm_mfma_kernel(
    const float* __restrict__ x, const ushortT* __restrict__ wbf,
    ushortT* __restrict__ xph)
{
    __shared__ ushortT xa[32][136];       // 8.7 KB staging, 272B rows (16B aligned)
    __shared__ ushortT tl[4][32][72];     // 18.4 KB epilogue transpose
    const int t = threadIdx.x;
    const int row0 = blockIdx.x * 32;

    {
        const int r = t >> 3, seg = t & 7;
        const int gr = row0 + r;
        const int gr_c = gr < NN ? gr : NN - 1;
        const float* src = x + (size_t)gr_c * CIN + seg * 16;
        const float4 v0 = *(const float4*)(src);
        const float4 v1 = *(const float4*)(src + 4);
        const float4 v2 = *(const float4*)(src + 8);
        const float4 v3 = *(const float4*)(src + 12);
        bf16x8 o0, o1;
        o0[0] = f2bf(v0.x); o0[1] = f2bf(v0.y); o0[2] = f2bf(v0.z); o0[3] = f2bf(v0.w);
        o0[4] = f2bf(v1.x); o0[5] = f2bf(v1.y); o0[6] = f2bf(v1.z); o0[7] = f2bf(v1.w);
        o1[0] = f2bf(v2.x); o1[1] = f2bf(v2.y); o1[2] = f2bf(v2.z); o1[3] = f2bf(v2.w);
        o1[4] = f2bf(v3.x); o1[5] = f2bf(v3.y); o1[6] = f2bf(v3.z); o1[7] = f2bf(v3.w);
        *(bf16x8*)(&xa[r][seg * 16]) = o0;
        *(bf16x8*)(&xa[r][seg * 16 + 8]) = o1;
    }
    __syncthreads();

    const int w = t >> 6, l = t & 63;
    const int part = w >> 1, ch = w & 1;
    const int rowlo = l & 15, kb = (l >> 4) * 8;

    bf16x8 a[2][4];
    #pragma unroll
    for (int rg = 0; rg < 2; ++rg)
        #pragma unroll
        for (int ks = 0; ks < 4; ++ks)
            a[rg][ks] = *(const bf16x8*)(&xa[rg * 16 + rowlo][ks * 32 + kb]);

    f32x4 acc[2][4] = {};
    const ushortT* wbase = wbf + (size_t)(part * 128 + ch * 64 + rowlo) * 128 + kb;
    #pragma unroll
    for (int ks = 0; ks < 4; ++ks) {
        #pragma unroll
        for (int ct = 0; ct < 4; ++ct) {
            const bf16x8 b = *(const bf16x8*)(wbase + (size_t)ct * 16 * 128 + ks * 32);
            acc[0][ct] = __builtin_amdgcn_mfma_f32_16x16x32_bf16(a[0][ks], b, acc[0][ct], 0, 0, 0);
            acc[1][ct] = __builtin_amdgcn_mfma_f32_16x16x32_bf16(a[1][ks], b, acc[1][ct], 0, 0, 0);
        }
    }

    #pragma unroll
    for (int rg = 0; rg < 2; ++rg)
        #pragma unroll
        for (int ct = 0; ct < 4; ++ct)
            #pragma unroll
            for (int j = 0; j < 4; ++j)
                tl[w][rg * 16 + (l >> 4) * 4 + j][ct * 16 + rowlo] = f2bf(acc[rg][ct][j]);
    __syncthreads();

    #pragma unroll
    for (int c = 0; c < 4; ++c) {
        const int cid = c * 256 + t;
        const int r = cid >> 5, col = (cid & 31) * 8;
        const int gr = row0 + r;
        if (gr < NN)
            *(bf16x8*)(xph + (size_t)gr * 256 + col) =
                *(const bf16x8*)(&tl[col >> 6][r][col & 63]);
    }
}

// ---------------------------------------------------------------------------
// Fused per-node GATv2: one wave per node, lane = h*16+dd covers 2 dims.
// Self-loop inline. Main loop unrolled 12 edges (24 gathers in flight).
// ---------------------------------------------------------------------------
#define SCORE_OF(ulv, cv)                                                 \
    {                                                                     \
        float vx = bflo(ulv) + rnx, vy = bfhi(ulv) + rny;                 \
        vx = vx > 0.f ? vx : NEG * vx;                                    \
        vy = vy > 0.f ? vy : NEG * vy;                                    \
        cv = vx * a2.x + vy * a2.y;                                       \
    }
#define RED16(cv)                                                         \
    cv += __shfl_xor(cv, 1); cv += __shfl_xor(cv, 2);                     \
    cv += __shfl_xor(cv, 4); cv += __shfl_xor(cv, 8);

#define GROUP4(i0, i1, i2, i3)                                            \
    {                                                                     \
        float c0, c1, c2, c3;                                             \
        SCORE_OF(ul[i0], c0) SCORE_OF(ul[i1], c1)                         \
        SCORE_OF(ul[i2], c2) SCORE_OF(ul[i3], c3)                         \
        c0 += __shfl_xor(c0, 1); c1 += __shfl_xor(c1, 1);                 \
        c2 += __shfl_xor(c2, 1); c3 += __shfl_xor(c3, 1);                 \
        c0 += __shfl_xor(c0, 2); c1 += __shfl_xor(c1, 2);                 \
        c2 += __shfl_xor(c2, 2); c3 += __shfl_xor(c3, 2);                 \
        c0 += __shfl_xor(c0, 4); c1 += __shfl_xor(c1, 4);                 \
        c2 += __shfl_xor(c2, 4); c3 += __shfl_xor(c3, 4);                 \
        c0 += __shfl_xor(c0, 8); c1 += __shfl_xor(c1, 8);                 \
        c2 += __shfl_xor(c2, 8); c3 += __shfl_xor(c3, 8);                 \
        const float e0 = __expf(c0), e1 = __expf(c1);                     \
        const float e2 = __expf(c2), e3 = __expf(c3);                     \
        den += (e0 + e1) + (e2 + e3);                                     \
        ax = fmaf(e0, bflo(us[i0]), ax); ay = fmaf(e0, bfhi(us[i0]), ay); \
        ax = fmaf(e1, bflo(us[i1]), ax); ay = fmaf(e1, bfhi(us[i1]), ay); \
        ax = fmaf(e2, bflo(us[i2]), ax); ay = fmaf(e2, bfhi(us[i2]), ay); \
        ax = fmaf(e3, bflo(us[i3]), ax); ay = fmaf(e3, bfhi(us[i3]), ay); \
    }

__global__ __launch_bounds__(256, 6) void gat_node_kernel(
    const int* __restrict__ row, const int* __restrict__ esrc,
    const ushortT* __restrict__ xph, const float* __restrict__ att,
    const float* __restrict__ bias, float* __restrict__ out)
{
    const int lane = threadIdx.x & 63;
    const int h = lane >> 4, dd = lane & 15;
    const int n = blockIdx.x * 4 + (threadIdx.x >> 6);
    if (n >= NN) return;

    const float2 a2 = *(const float2*)(att + h * DD + dd * 2);
    const uintT uln = *(const uintT*)(xph + (size_t)n * 256 + lane * 2);
    const uintT urn = *(const uintT*)(xph + (size_t)n * 256 + 128 + lane * 2);
    const float rnx = bflo(urn), rny = bfhi(urn);

    // self-loop first
    float den, ax, ay;
    {
        float c;
        SCORE_OF(uln, c)
        RED16(c)
        const float pe = __expf(c);
        den = pe;
        ax = pe * bflo(urn);
        ay = pe * bfhi(urn);
    }

    const int p0 = row[n], p1 = row[n + 1];
    int p = p0;

    for (; p + 12 <= p1; p += 12) {
        int s[12];
        #pragma unroll
        for (int j = 0; j < 12; ++j) s[j] = esrc[p + j];
        uintT ul[12], us[12];
        #pragma unroll
        for (int j = 0; j < 12; ++j) {
            ul[j] = *(const uintT*)(xph + (size_t)s[j] * 256 + lane * 2);
            us[j] = *(const uintT*)(xph + (size_t)s[j] * 256 + 128 + lane * 2);
        }
        GROUP4(0, 1, 2, 3) GROUP4(4, 5, 6, 7) GROUP4(8, 9, 10, 11)
    }
    for (; p + 4 <= p1; p += 4) {
        int s[4];
        #pragma unroll
        for (int j = 0; j < 4; ++j) s[j] = esrc[p + j];
        uintT ul[4], us[4];
        #pragma unroll
        for (int j = 0; j < 4; ++j) {
            ul[j] = *(const uintT*)(xph + (size_t)s[j] * 256 + lane * 2);
            us[j] = *(const uintT*)(xph + (size_t)s[j] * 256 + 128 + lane * 2);
        }
        GROUP4(0, 1, 2, 3)
    }
    for (; p < p1; ++p) {
        const int s = esrc[p];
        const uintT ul = *(const uintT*)(xph + (size_t)s * 256 + lane * 2);
        const uintT us = *(const uintT*)(xph + (size_t)s * 256 + 128 + lane * 2);
        float c;
        SCORE_OF(ul, c)
        RED16(c)
        const float pe = __expf(c);
        den += pe;
        ax = fmaf(pe, bflo(us), ax);
        ay = fmaf(pe, bfhi(us), ay);
    }

    const float inv = 1.f / fmaxf(den, 1e-16f);
    ax *= inv; ay *= inv;
    ax += __shfl_xor(ax, 16); ay += __shfl_xor(ay, 16);
    ax += __shfl_xor(ax, 32); ay += __shfl_xor(ay, 32);
    if (h == 0) {
        float2 o;
        o.x = ax * 0.25f + bias[dd * 2];
        o.y = ay * 0.25f + bias[dd * 2 + 1];
        *(float2*)(out + (size_t)n * DD + dd * 2) = o;
    }
}

extern "C" void kernel_launch(void* const* d_in, const int* in_sizes, int n_in,
                              void* d_out, int out_size, void* d_ws, size_t ws_size,
                              hipStream_t stream)
{
    const float* x    = (const float*)d_in[0];
    const int*   ei   = (const int*)d_in[1];
    const float* Wl   = (const float*)d_in[2];
    const float* Wr   = (const float*)d_in[3];
    const float* att  = (const float*)d_in[4];
    const float* bias = (const float*)d_in[5];
    float* out = (float*)d_out;

    float*   ws   = (float*)d_ws;
    int*     flag = (int*)ws;
    int*     cnt  = (int*)(ws + CNT_OFF);
    int*     fill = (int*)(ws + FILL_OFF);
    int*     row  = (int*)(ws + ROW_OFF);
    int*     esrc = (int*)(ws + ESRC_OFF);
    int*     btot = (int*)(ws + BTOT_OFF);
    ushortT* wbf  = (ushortT*)(ws + WBF_OFF);
    ushortT* xph  = (ushortT*)(ws + XPH_OFF);

    void* args[] = {(void*)&ei, (void*)&Wl, (void*)&Wr, (void*)&flag,
                    (void*)&cnt, (void*)&fill, (void*)&row, (void*)&esrc,
                    (void*)&btot, (void*)&wbf};
    hipLaunchCooperativeKernel((void*)prep_kernel, dim3(256), dim3(1024),
                               args, 0, stream);

    hipLaunchKernelGGL(gemm_mfma_kernel, dim3((NN + 31) / 32), dim3(256), 0, stream,
                       x, wbf, xph);
    hipLaunchKernelGGL(gat_node_kernel, dim3((NN + 3) / 4), dim3(256), 0, stream,
                       row, esrc, xph, att, bias, out);
}

// Round 14
// 199.720 us; speedup vs baseline: 1.6721x; 1.6721x over previous
//
#include <hip/hip_runtime.h>
#include <hip/hip_bf16.h>

#define NN 50000
#define CIN 128
#define HH 4
#define DD 32
#define HD 128
#define EE 800000
#define NEG 0.2f

typedef unsigned short ushortT;
typedef unsigned int uintT;
typedef __attribute__((ext_vector_type(8))) short bf16x8;
typedef __attribute__((ext_vector_type(4))) float f32x4;

// ---------------------------------------------------------------------------
// ws layout (units of 4B):
//   [0]       : flag (1 = edge_index is int64, 0 = int32)
//   CNT_OFF  = 16       : per-node in-degree (excl self) (NN ints) [memset 0]
//   FILL_OFF = 50016    : scatter fill counters (NN ints)          [memset 0]
//   ROW_OFF  = 100032   : CSR row offsets (NN+1 ints)
//   ESRC_OFF = 150048   : dst-sorted src indices (EE ints)
//   BTOT_OFF = 1000048  : scan block totals (64 ints)
//   WBF_OFF  = 1000112  : W bf16 [256][128] (16384 float-slots)
//   XPH_OFF  = 1016496  : interleaved bf16 rows xl|xr [NN][256] (3.2M slots)
// total 4,216,496 floats = 16.9 MB
// ---------------------------------------------------------------------------
#define CNT_OFF  16
#define FILL_OFF 50016
#define ROW_OFF  100032
#define ESRC_OFF 150048
#define BTOT_OFF 1000048
#define WBF_OFF  1000112
#define XPH_OFF  1016496
#define SCAN_NB  49          // ceil((NN+1)/1024)

__device__ __forceinline__ ushortT f2bf(float f) {
    uintT u = __float_as_uint(f);
    u = (u + 0x7fff + ((u >> 16) & 1)) >> 16;   // RNE
    return (ushortT)u;
}
__device__ __forceinline__ float bflo(uintT u) { return __uint_as_float(u << 16); }
__device__ __forceinline__ float bfhi(uintT u) { return __uint_as_float(u & 0xffff0000u); }

// ---------------------------------------------------------------------------
// Detect int64 vs int32 edge_index: int64 values < 2^31 have zero odd words.
// ---------------------------------------------------------------------------
__global__ void detect_kernel(const int* __restrict__ ei_raw, int* __restrict__ flag)
{
    const int l = threadIdx.x;                // 64 threads
    const int w = ei_raw[2 * l + 1];
    const unsigned long long b = __ballot(w != 0);
    if (l == 0) flag[0] = (b == 0ULL) ? 1 : 0;
}

// histogram dst straight from raw edge index; 4 edges/thread (grid-stride)
__global__ __launch_bounds__(256) void hist_kernel(
    const int* __restrict__ ei_raw, const int* __restrict__ flag, int* __restrict__ cnt)
{
    const int t0 = blockIdx.x * 256 + threadIdx.x;
    const int stride = gridDim.x * 256;
    const int f = flag[0];
    #pragma unroll
    for (int k = 0; k < 4; ++k) {
        const int e = t0 + k * stride;
        if (e < EE) {
            const int d = f ? ei_raw[2 * (EE + e)] : ei_raw[EE + e];
            atomicAdd(&cnt[d], 1);
        }
    }
}

// convert Wl|Wr to bf16: wbf[256][128], rows 0..127 = Wl, 128..255 = Wr
__global__ __launch_bounds__(256) void wprep_kernel(
    const float* __restrict__ Wl, const float* __restrict__ Wr, ushortT* __restrict__ wbf)
{
    const int i = blockIdx.x * 256 + threadIdx.x;   // 4096 threads, 8 elems each
    const float* src = (i < 2048) ? Wl : Wr;
    const int off = (i < 2048) ? i : i - 2048;
    const float4 v0 = *(const float4*)(src + (size_t)off * 8);
    const float4 v1 = *(const float4*)(src + (size_t)off * 8 + 4);
    bf16x8 o;
    o[0] = f2bf(v0.x); o[1] = f2bf(v0.y); o[2] = f2bf(v0.z); o[3] = f2bf(v0.w);
    o[4] = f2bf(v1.x); o[5] = f2bf(v1.y); o[6] = f2bf(v1.z); o[7] = f2bf(v1.w);
    *(bf16x8*)(wbf + ((i < 2048) ? 0 : 16384) + (size_t)off * 8) = o;
}

// ---------------------------------------------------------------------------
// scan1: block-local exclusive scan of cnt (self-loops handled inline later)
// ---------------------------------------------------------------------------
__global__ __launch_bounds__(1024) void scan1_kernel(
    const int* __restrict__ cnt, int* __restrict__ row, int* __restrict__ btot)
{
    __shared__ int wtot[16];
    const int t = threadIdx.x, lane = t & 63, wv = t >> 6;
    const int i = blockIdx.x * 1024 + t;
    const int v = (i < NN) ? cnt[i] : 0;
    int acc = v;
    #pragma unroll
    for (int off = 1; off < 64; off <<= 1) {
        const int u = __shfl_up(acc, off, 64);
        if (lane >= off) acc += u;
    }
    if (lane == 63) wtot[wv] = acc;
    __syncthreads();
    if (wv == 0 && lane < 16) {
        const int wvv = wtot[lane];
        int wacc = wvv;
        #pragma unroll
        for (int off = 1; off < 16; off <<= 1) {
            const int u = __shfl_up(wacc, off, 64);
            if (lane >= off) wacc += u;
        }
        wtot[lane] = wacc - wvv;            // exclusive wave offset
    }
    __syncthreads();
    const int ex = wtot[wv] + acc - v;      // block-local exclusive prefix
    if (i <= NN) row[i] = ex;
    if (t == 1023) btot[blockIdx.x] = ex + v;
}

// scan3: each block wave-reduces its own btot prefix, adds to row
__global__ __launch_bounds__(256) void scan3_kernel(
    int* __restrict__ row, const int* __restrict__ btot)
{
    const int i = blockIdx.x * 256 + threadIdx.x;
    const int chunk = blockIdx.x >> 2;              // 1024-chunk id (const per block)
    const int lane = threadIdx.x & 63;
    int v = (lane < chunk) ? btot[lane] : 0;
    #pragma unroll
    for (int off = 1; off < 64; off <<= 1) v += __shfl_xor(v, off);
    if (i <= NN) row[i] += v;
}

// place src of each real edge into its dst segment; 4 edges/thread
__global__ __launch_bounds__(256) void scatter_kernel(
    const int* __restrict__ ei_raw, const int* __restrict__ flag,
    const int* __restrict__ row, int* __restrict__ fill, int* __restrict__ esrc)
{
    const int t0 = blockIdx.x * 256 + threadIdx.x;
    const int stride = gridDim.x * 256;
    const int f = flag[0];
    #pragma unroll
    for (int k = 0; k < 4; ++k) {
        const int e = t0 + k * stride;
        if (e < EE) {
            int s, d;
            if (f) { s = ei_raw[2 * e]; d = ei_raw[2 * (EE + e)]; }
            else   { s = ei_raw[e];     d = ei_raw[EE + e]; }
            const int pos = row[d] + atomicAdd(&fill[d], 1);
            esrc[pos] = s;
        }
    }
}

// ---------------------------------------------------------------------------
// MFMA GEMM with fused f32->bf16 x conversion via LDS staging.
// Block = 256 thr = 4 waves; computes 32 rows x 256 cols (all parts/halves).
// ---------------------------------------------------------------------------
__global__ __launch_bounds__(256) void gemm_mfma_kernel(
    const float* __restrict__ x, const ushortT* __restrict__ wbf,
    ushortT* __restrict__ xph)
{
    __shared__ ushortT xa[32][136];       // 8.7 KB staging, 272B rows (16B aligned)
    __shared__ ushortT tl[4][32][72];     // 18.4 KB epilogue transpose
    const int t = threadIdx.x;
    const int row0 = blockIdx.x * 32;

    {
        const int r = t >> 3, seg = t & 7;
        const int gr = row0 + r;
        const int gr_c = gr < NN ? gr : NN - 1;
        const float* src = x + (size_t)gr_c * CIN + seg * 16;
        const float4 v0 = *(const float4*)(src);
        const float4 v1 = *(const float4*)(src + 4);
        const float4 v2 = *(const float4*)(src + 8);
        const float4 v3 = *(const float4*)(src + 12);
        bf16x8 o0, o1;
        o0[0] = f2bf(v0.x); o0[1] = f2bf(v0.y); o0[2] = f2bf(v0.z); o0[3] = f2bf(v0.w);
        o0[4] = f2bf(v1.x); o0[5] = f2bf(v1.y); o0[6] = f2bf(v1.z); o0[7] = f2bf(v1.w);
        o1[0] = f2bf(v2.x); o1[1] = f2bf(v2.y); o1[2] = f2bf(v2.z); o1[3] = f2bf(v2.w);
        o1[4] = f2bf(v3.x); o1[5] = f2bf(v3.y); o1[6] = f2bf(v3.z); o1[7] = f2bf(v3.w);
        *(bf16x8*)(&xa[r][seg * 16]) = o0;
        *(bf16x8*)(&xa[r][seg * 16 + 8]) = o1;
    }
    __syncthreads();

    const int w = t >> 6, l = t & 63;
    const int part = w >> 1, ch = w & 1;
    const int rowlo = l & 15, kb = (l >> 4) * 8;

    bf16x8 a[2][4];
    #pragma unroll
    for (int rg = 0; rg < 2; ++rg)
        #pragma unroll
        for (int ks = 0; ks < 4; ++ks)
            a[rg][ks] = *(const bf16x8*)(&xa[rg * 16 + rowlo][ks * 32 + kb]);

    f32x4 acc[2][4] = {};
    const ushortT* wbase = wbf + (size_t)(part * 128 + ch * 64 + rowlo) * 128 + kb;
    #pragma unroll
    for (int ks = 0; ks < 4; ++ks) {
        #pragma unroll
        for (int ct = 0; ct < 4; ++ct) {
            const bf16x8 b = *(const bf16x8*)(wbase + (size_t)ct * 16 * 128 + ks * 32);
            acc[0][ct] = __builtin_amdgcn_mfma_f32_16x16x32_bf16(a[0][ks], b, acc[0][ct], 0, 0, 0);
            acc[1][ct] = __builtin_amdgcn_mfma_f32_16x16x32_bf16(a[1][ks], b, acc[1][ct], 0, 0, 0);
        }
    }

    #pragma unroll
    for (int rg = 0; rg < 2; ++rg)
        #pragma unroll
        for (int ct = 0; ct < 4; ++ct)
            #pragma unroll
            for (int j = 0; j < 4; ++j)
                tl[w][rg * 16 + (l >> 4) * 4 + j][ct * 16 + rowlo] = f2bf(acc[rg][ct][j]);
    __syncthreads();

    #pragma unroll
    for (int c = 0; c < 4; ++c) {
        const int cid = c * 256 + t;
        const int r = cid >> 5, col = (cid & 31) * 8;
        const int gr = row0 + r;
        if (gr < NN)
            *(bf16x8*)(xph + (size_t)gr * 256 + col) =
                *(const bf16x8*)(&tl[col >> 6][r][col & 63]);
    }
}

// ---------------------------------------------------------------------------
// Fused per-node GATv2: one wave per node, lane = h*16+dd covers 2 dims.
// Self-loop inline. Main loop unrolled 12 edges (24 gathers in flight).
// ---------------------------------------------------------------------------
#define SCORE_OF(ulv, cv)                                                 \
    {                                                                     \
        float vx = bflo(ulv) + rnx, vy = bfhi(ulv) + rny;                 \
        vx = vx > 0.f ? vx : NEG * vx;                                    \
        vy = vy > 0.f ? vy : NEG * vy;                                    \
        cv = vx * a2.x + vy * a2.y;                                       \
    }
#define RED16(cv)                                                         \
    cv += __shfl_xor(cv, 1); cv += __shfl_xor(cv, 2);                     \
    cv += __shfl_xor(cv, 4); cv += __shfl_xor(cv, 8);

#define GROUP4(i0, i1, i2, i3)                                            \
    {                                                                     \
        float c0, c1, c2, c3;                                             \
        SCORE_OF(ul[i0], c0) SCORE_OF(ul[i1], c1)                         \
        SCORE_OF(ul[i2], c2) SCORE_OF(ul[i3], c3)                         \
        c0 += __shfl_xor(c0, 1); c1 += __shfl_xor(c1, 1);                 \
        c2 += __shfl_xor(c2, 1); c3 += __shfl_xor(c3, 1);                 \
        c0 += __shfl_xor(c0, 2); c1 += __shfl_xor(c1, 2);                 \
        c2 += __shfl_xor(c2, 2); c3 += __shfl_xor(c3, 2);                 \
        c0 += __shfl_xor(c0, 4); c1 += __shfl_xor(c1, 4);                 \
        c2 += __shfl_xor(c2, 4); c3 += __shfl_xor(c3, 4);                 \
        c0 += __shfl_xor(c0, 8); c1 += __shfl_xor(c1, 8);                 \
        c2 += __shfl_xor(c2, 8); c3 += __shfl_xor(c3, 8);                 \
        const float e0 = __expf(c0), e1 = __expf(c1);                     \
        const float e2 = __expf(c2), e3 = __expf(c3);                     \
        den += (e0 + e1) + (e2 + e3);                                     \
        ax = fmaf(e0, bflo(us[i0]), ax); ay = fmaf(e0, bfhi(us[i0]), ay); \
        ax = fmaf(e1, bflo(us[i1]), ax); ay = fmaf(e1, bfhi(us[i1]), ay); \
        ax = fmaf(e2, bflo(us[i2]), ax); ay = fmaf(e2, bfhi(us[i2]), ay); \
        ax = fmaf(e3, bflo(us[i3]), ax); ay = fmaf(e3, bfhi(us[i3]), ay); \
    }

__global__ __launch_bounds__(256, 6) void gat_node_kernel(
    const int* __restrict__ row, const int* __restrict__ esrc,
    const ushortT* __restrict__ xph, const float* __restrict__ att,
    const float* __restrict__ bias, float* __restrict__ out)
{
    const int lane = threadIdx.x & 63;
    const int h = lane >> 4, dd = lane & 15;
    const int n = blockIdx.x * 4 + (threadIdx.x >> 6);
    if (n >= NN) return;

    const float2 a2 = *(const float2*)(att + h * DD + dd * 2);
    const uintT uln = *(const uintT*)(xph + (size_t)n * 256 + lane * 2);
    const uintT urn = *(const uintT*)(xph + (size_t)n * 256 + 128 + lane * 2);
    const float rnx = bflo(urn), rny = bfhi(urn);

    // self-loop first
    float den, ax, ay;
    {
        float c;
        SCORE_OF(uln, c)
        RED16(c)
        const float pe = __expf(c);
        den = pe;
        ax = pe * bflo(urn);
        ay = pe * bfhi(urn);
    }

    const int p0 = row[n], p1 = row[n + 1];
    int p = p0;

    for (; p + 12 <= p1; p += 12) {
        int s[12];
        #pragma unroll
        for (int j = 0; j < 12; ++j) s[j] = esrc[p + j];
        uintT ul[12], us[12];
        #pragma unroll
        for (int j = 0; j < 12; ++j) {
            ul[j] = *(const uintT*)(xph + (size_t)s[j] * 256 + lane * 2);
            us[j] = *(const uintT*)(xph + (size_t)s[j] * 256 + 128 + lane * 2);
        }
        GROUP4(0, 1, 2, 3) GROUP4(4, 5, 6, 7) GROUP4(8, 9, 10, 11)
    }
    for (; p + 4 <= p1; p += 4) {
        int s[4];
        #pragma unroll
        for (int j = 0; j < 4; ++j) s[j] = esrc[p + j];
        uintT ul[4], us[4];
        #pragma unroll
        for (int j = 0; j < 4; ++j) {
            ul[j] = *(const uintT*)(xph + (size_t)s[j] * 256 + lane * 2);
            us[j] = *(const uintT*)(xph + (size_t)s[j] * 256 + 128 + lane * 2);
        }
        GROUP4(0, 1, 2, 3)
    }
    for (; p < p1; ++p) {
        const int s = esrc[p];
        const uintT ul = *(const uintT*)(xph + (size_t)s * 256 + lane * 2);
        const uintT us = *(const uintT*)(xph + (size_t)s * 256 + 128 + lane * 2);
        float c;
        SCORE_OF(ul, c)
        RED16(c)
        const float pe = __expf(c);
        den += pe;
        ax = fmaf(pe, bflo(us), ax);
        ay = fmaf(pe, bfhi(us), ay);
    }

    const float inv = 1.f / fmaxf(den, 1e-16f);
    ax *= inv; ay *= inv;
    ax += __shfl_xor(ax, 16); ay += __shfl_xor(ay, 16);
    ax += __shfl_xor(ax, 32); ay += __shfl_xor(ay, 32);
    if (h == 0) {
        float2 o;
        o.x = ax * 0.25f + bias[dd * 2];
        o.y = ay * 0.25f + bias[dd * 2 + 1];
        *(float2*)(out + (size_t)n * DD + dd * 2) = o;
    }
}

extern "C" void kernel_launch(void* const* d_in, const int* in_sizes, int n_in,
                              void* d_out, int out_size, void* d_ws, size_t ws_size,
                              hipStream_t stream)
{
    const float* x    = (const float*)d_in[0];
    const int*   ei   = (const int*)d_in[1];
    const float* Wl   = (const float*)d_in[2];
    const float* Wr   = (const float*)d_in[3];
    const float* att  = (const float*)d_in[4];
    const float* bias = (const float*)d_in[5];
    float* out = (float*)d_out;

    float*   ws   = (float*)d_ws;
    int*     flag = (int*)ws;
    int*     cnt  = (int*)(ws + CNT_OFF);
    int*     fill = (int*)(ws + FILL_OFF);
    int*     row  = (int*)(ws + ROW_OFF);
    int*     esrc = (int*)(ws + ESRC_OFF);
    int*     btot = (int*)(ws + BTOT_OFF);
    ushortT* wbf  = (ushortT*)(ws + WBF_OFF);
    ushortT* xph  = (ushortT*)(ws + XPH_OFF);

    // zero cnt + fill (contiguous 400 KB)
    hipMemsetAsync(cnt, 0, (size_t)(2 * NN) * sizeof(int), stream);

    hipLaunchKernelGGL(detect_kernel, dim3(1), dim3(64), 0, stream, ei, flag);
    hipLaunchKernelGGL(hist_kernel, dim3((EE + 1023) / 1024), dim3(256), 0, stream,
                       ei, flag, cnt);
    hipLaunchKernelGGL(wprep_kernel, dim3(16), dim3(256), 0, stream, Wl, Wr, wbf);
    hipLaunchKernelGGL(scan1_kernel, dim3(SCAN_NB), dim3(1024), 0, stream, cnt, row, btot);
    hipLaunchKernelGGL(scan3_kernel, dim3((NN + 256) / 256), dim3(256), 0, stream, row, btot);
    hipLaunchKernelGGL(scatter_kernel, dim3((EE + 1023) / 1024), dim3(256), 0, stream,
                       ei, flag, row, fill, esrc);
    hipLaunchKernelGGL(gemm_mfma_kernel, dim3((NN + 31) / 32), dim3(256), 0, stream,
                       x, wbf, xph);
    hipLaunchKernelGGL(gat_node_kernel, dim3((NN + 3) / 4), dim3(256), 0, stream,
                       row, esrc, xph, att, bias, out);
}